// Round 2
// baseline (864.241 us; speedup 1.0000x reference)
//
#include <hip/hip_runtime.h>

#define SEQ   8192
#define DIM   1280
#define NH    16
#define HD    80
#define HDP   96
#define NSEG  8
#define SEGL  1024
#define SCALING 0.11180339887498949f  // 80^-0.5

typedef __bf16 bf16x8 __attribute__((ext_vector_type(8)));
typedef float  f32x4  __attribute__((ext_vector_type(4)));

__device__ __forceinline__ unsigned short f2bf(float x) {
    union { float f; unsigned u; } v; v.f = x;
    unsigned r = v.u + 0x7fffu + ((v.u >> 16) & 1u);
    return (unsigned short)(r >> 16);
}
__device__ __forceinline__ float bf2f(unsigned short h) {
    union { unsigned u; float f; } v; v.u = ((unsigned)h) << 16;
    return v.f;
}
__device__ __forceinline__ void glds16(const void* g, void* l) {
    __builtin_amdgcn_global_load_lds(
        (const __attribute__((address_space(1))) unsigned int*)g,
        (__attribute__((address_space(3))) unsigned int*)l, 16, 0, 0);
}

// ---------------------------------------------------------------------------
// Kernel 1: fp32->bf16 conversion of hidden/qkv_w/proj_w + zero q/k pads
// ---------------------------------------------------------------------------
__global__ void prep_kernel(const float* __restrict__ hs, const float* __restrict__ qw,
                            const float* __restrict__ pw,
                            short* __restrict__ hsb, short* __restrict__ qwb,
                            short* __restrict__ pwb,
                            short* __restrict__ qbf, short* __restrict__ kbf)
{
    const int N1 = SEQ * DIM / 4;          // 2621440 float4 chunks
    const int N2 = 3 * DIM * DIM / 4;      // 1228800
    const int N3 = DIM * DIM / 4;          // 409600
    const int NZH = NSEG * NH * SEGL * 2;  // 262144 zero-units (16B) per array
    const int total = N1 + N2 + N3 + 2 * NZH;
    for (int u = blockIdx.x * blockDim.x + threadIdx.x; u < total;
         u += gridDim.x * blockDim.x) {
        if (u < N1 + N2 + N3) {
            const float* src; short* dst; int i;
            if (u < N1)           { src = hs; dst = hsb; i = u; }
            else if (u < N1 + N2) { src = qw; dst = qwb; i = u - N1; }
            else                  { src = pw; dst = pwb; i = u - N1 - N2; }
            float4 f = ((const float4*)src)[i];
            ushort4 r;
            r.x = f2bf(f.x); r.y = f2bf(f.y); r.z = f2bf(f.z); r.w = f2bf(f.w);
            ((ushort4*)dst)[i] = r;
        } else {
            int z = u - (N1 + N2 + N3);
            short* base = (z < NZH) ? qbf : kbf;
            int rr = z & (NZH - 1);          // NZH is a power of 2
            int row = rr >> 1, half = rr & 1;
            float4 zero = make_float4(0.f, 0.f, 0.f, 0.f);
            *(float4*)(base + (long)row * HDP + HD + half * 8) = zero;
        }
    }
}

// ---------------------------------------------------------------------------
// Kernel 2/5: bf16 GEMM C = A @ B^T (A:[M][K], B:[N][K] both row-major, K=1280)
// MODE 0: QKV epilogue (bias + scatter into q/k/v [seg][head][row][HDP|HD])
// MODE 1: proj epilogue (bias + fp32 store)
// ---------------------------------------------------------------------------
template <int MODE>
__launch_bounds__(256)
__global__ void gemm_kernel(const short* __restrict__ A, const short* __restrict__ B,
                            const float* __restrict__ bias,
                            short* __restrict__ q, short* __restrict__ k,
                            short* __restrict__ v, float* __restrict__ outf)
{
    __shared__ __align__(16) short As[128 * 64];
    __shared__ __align__(16) short Bs[128 * 64];
    const int K = DIM;
    int tid = threadIdx.x;
    int lane = tid & 63, wid = tid >> 6;
    int l15 = lane & 15, lh = lane >> 4;
    int m0 = blockIdx.y * 128, n0 = blockIdx.x * 128;
    int wr = wid >> 1, wc = wid & 1;
    f32x4 acc[4][4] = {};
    int srow = lane >> 3;        // 0..7 (row within 8-row chunk)
    int scol = (lane & 7) * 8;   // element col within 64

    for (int kb = 0; kb < K; kb += 64) {
        for (int i = 0; i < 4; i++) {
            int c = wid * 4 + i;   // 16 chunks of 8 rows x 64 cols
            glds16(A + (long)(m0 + c * 8 + srow) * K + kb + scol, As + c * 512);
            glds16(B + (long)(n0 + c * 8 + srow) * K + kb + scol, Bs + c * 512);
        }
        __syncthreads();
        for (int ks = 0; ks < 2; ks++) {
            bf16x8 af[4], bf[4];
            int ko = ks * 32 + lh * 8;
            for (int rb = 0; rb < 4; rb++)
                af[rb] = *(const bf16x8*)&As[(wr * 64 + rb * 16 + l15) * 64 + ko];
            for (int cb = 0; cb < 4; cb++)
                bf[cb] = *(const bf16x8*)&Bs[(wc * 64 + cb * 16 + l15) * 64 + ko];
            for (int rb = 0; rb < 4; rb++)
                for (int cb = 0; cb < 4; cb++)
                    acc[rb][cb] = __builtin_amdgcn_mfma_f32_16x16x32_bf16(
                        af[rb], bf[cb], acc[rb][cb], 0, 0, 0);
        }
        __syncthreads();
    }

    int mb = m0 + wr * 64, nb = n0 + wc * 64;
    if (MODE == 0) {
        for (int cb = 0; cb < 4; cb++) {
            int n = nb + cb * 16 + l15;
            float bn = bias[n];
            int which = n / DIM;
            int rem = n - which * DIM;
            int h = rem / HD;
            int d = rem - h * HD;
            for (int rb = 0; rb < 4; rb++)
                for (int j = 0; j < 4; j++) {
                    int m = mb + rb * 16 + lh * 4 + j;
                    int seg = m >> 10, r = m & 1023;
                    float val = acc[rb][cb][j] + bn;
                    long base = ((long)(seg * NH + h) * SEGL + r);
                    unsigned short bv = f2bf(val);
                    if (which == 0)      q[base * HDP + d] = (short)bv;
                    else if (which == 1) k[base * HDP + d] = (short)bv;
                    else                 v[base * HD + d] = (short)bv;
                }
        }
    } else {
        for (int cb = 0; cb < 4; cb++) {
            int n = nb + cb * 16 + l15;
            float bn = bias[n];
            for (int rb = 0; rb < 4; rb++)
                for (int j = 0; j < 4; j++) {
                    int m = mb + rb * 16 + lh * 4 + j;
                    outf[(long)m * DIM + n] = acc[rb][cb][j] + bn;
                }
        }
    }
}

// ---------------------------------------------------------------------------
// Kernel 3: RoPE on q,k (in place); SCALING folded into q
// ---------------------------------------------------------------------------
__global__ void rope_kernel(short* __restrict__ q, short* __restrict__ k,
                            const float* __restrict__ cs, const float* __restrict__ sn)
{
    int idx = blockIdx.x * blockDim.x + threadIdx.x;   // SEQ*NH*40 threads
    int p = idx / (NH * 40);
    int rem = idx - p * (NH * 40);
    int h = rem / 40;
    int dp = rem - h * 40;
    int seg = p >> 10, r = p & 1023;
    long base = ((long)(seg * NH + h) * SEGL + r) * HDP;
    float c0 = cs[p * HD + dp],      s0 = sn[p * HD + dp];
    float c1 = cs[p * HD + dp + 40], s1 = sn[p * HD + dp + 40];
    float a = bf2f((unsigned short)q[base + dp]);
    float b = bf2f((unsigned short)q[base + dp + 40]);
    q[base + dp]      = (short)f2bf((a * c0 - b * s0) * SCALING);
    q[base + dp + 40] = (short)f2bf((b * c1 + a * s1) * SCALING);
    a = bf2f((unsigned short)k[base + dp]);
    b = bf2f((unsigned short)k[base + dp + 40]);
    k[base + dp]      = (short)f2bf(a * c0 - b * s0);
    k[base + dp + 40] = (short)f2bf(b * c1 + a * s1);
}

// ---------------------------------------------------------------------------
// Kernel 4: flash attention per (seg, head, 64-row q-tile). 4 waves.
// Q frags in registers (global 16B loads), K frags from global, V^T via LDS,
// P through LDS for the PV A-operand. Online softmax, cross-wave via LDS.
// ---------------------------------------------------------------------------
__launch_bounds__(256)
__global__ void attn_kernel(const short* __restrict__ qg, const short* __restrict__ kg,
                            const short* __restrict__ vg, short* __restrict__ out)
{
    __shared__ __align__(16) short plds[64 * 136];
    __shared__ __align__(16) short vt[80 * 136];
    __shared__ float pmax[4][64];
    __shared__ float psum[4][64];
    __shared__ float mbuf[64], lbuf[64], fbuf[64];
    int tid = threadIdx.x;
    int lane = tid & 63, wid = tid >> 6;
    int l15 = lane & 15, lh = lane >> 4;
    int qt = blockIdx.x, h = blockIdx.y, seg = blockIdx.z;
    const short* qh = qg + (long)(seg * NH + h) * SEGL * HDP;
    const short* kh = kg + (long)(seg * NH + h) * SEGL * HDP;
    const short* vh = vg + (long)(seg * NH + h) * SEGL * HD;

    bf16x8 qf[4][3];
    for (int rb = 0; rb < 4; rb++)
        for (int ks = 0; ks < 3; ks++)
            qf[rb][ks] = *(const bf16x8*)&qh[(qt * 64 + rb * 16 + l15) * HDP + ks * 32 + lh * 8];

    f32x4 o[5] = {};
    if (tid < 64) { mbuf[tid] = -1e30f; lbuf[tid] = 0.f; }
    __syncthreads();

    for (int t = 0; t < 8; t++) {
        // stage V^T tile: vt[d][j] = V[t*128+j][d]
        const short* vtile = vh + (long)t * 128 * HD;
        for (int i = 0; i < 20; i++) {
            int ii = tid + 256 * i;            // 0..5119
            int j = ii / 40, dp2 = (ii - j * 40) * 2;
            unsigned int w = *(const unsigned int*)&vtile[j * HD + dp2];
            vt[dp2 * 136 + j]       = (short)(w & 0xffffu);
            vt[(dp2 + 1) * 136 + j] = (short)(w >> 16);
        }
        // S = Q K^T  (wave owns 32-col quarter, all 64 rows)
        f32x4 s[4][2] = {};
        const short* kt = kh + (long)t * 128 * HDP;
        for (int ks = 0; ks < 3; ks++) {
            bf16x8 kf0 = *(const bf16x8*)&kt[(wid * 32 + l15) * HDP + ks * 32 + lh * 8];
            bf16x8 kf1 = *(const bf16x8*)&kt[(wid * 32 + 16 + l15) * HDP + ks * 32 + lh * 8];
            for (int rb = 0; rb < 4; rb++) {
                s[rb][0] = __builtin_amdgcn_mfma_f32_16x16x32_bf16(qf[rb][ks], kf0, s[rb][0], 0, 0, 0);
                s[rb][1] = __builtin_amdgcn_mfma_f32_16x16x32_bf16(qf[rb][ks], kf1, s[rb][1], 0, 0, 0);
            }
        }
        // per-wave row max over the 32-col quarter
        for (int rb = 0; rb < 4; rb++)
            for (int j = 0; j < 4; j++) {
                float v2 = fmaxf(s[rb][0][j], s[rb][1][j]);
                v2 = fmaxf(v2, __shfl_xor(v2, 1));
                v2 = fmaxf(v2, __shfl_xor(v2, 2));
                v2 = fmaxf(v2, __shfl_xor(v2, 4));
                v2 = fmaxf(v2, __shfl_xor(v2, 8));
                if (l15 == 0) pmax[wid][rb * 16 + lh * 4 + j] = v2;
            }
        __syncthreads();
        if (tid < 64) {
            float rm = fmaxf(fmaxf(pmax[0][tid], pmax[1][tid]),
                             fmaxf(pmax[2][tid], pmax[3][tid]));
            float mo = mbuf[tid];
            float mn = fmaxf(mo, rm);
            float f = __expf(mo - mn);
            mbuf[tid] = mn; fbuf[tid] = f; lbuf[tid] *= f;
        }
        __syncthreads();
        // P = exp(S - m) -> bf16 LDS; partial row sums
        for (int rb = 0; rb < 4; rb++)
            for (int j = 0; j < 4; j++) {
                int row = rb * 16 + lh * 4 + j;
                float mr = mbuf[row];
                float p0 = __expf(s[rb][0][j] - mr);
                float p1 = __expf(s[rb][1][j] - mr);
                plds[row * 136 + wid * 32 + l15]      = (short)f2bf(p0);
                plds[row * 136 + wid * 32 + 16 + l15] = (short)f2bf(p1);
                float ps = p0 + p1;
                ps += __shfl_xor(ps, 1);
                ps += __shfl_xor(ps, 2);
                ps += __shfl_xor(ps, 4);
                ps += __shfl_xor(ps, 8);
                if (l15 == 0) psum[wid][row] = ps;
            }
        // rescale O accumulator (wave owns rows wid*16..wid*16+15)
        {
            float fr[4];
            for (int j = 0; j < 4; j++) fr[j] = fbuf[wid * 16 + lh * 4 + j];
            for (int cb = 0; cb < 5; cb++)
                for (int j = 0; j < 4; j++) o[cb][j] *= fr[j];
        }
        __syncthreads();
        if (tid < 64)
            lbuf[tid] += psum[0][tid] + psum[1][tid] + psum[2][tid] + psum[3][tid];
        // PV
        for (int ks = 0; ks < 4; ks++) {
            bf16x8 pa = *(const bf16x8*)&plds[(wid * 16 + l15) * 136 + ks * 32 + lh * 8];
            for (int cb = 0; cb < 5; cb++) {
                bf16x8 vb = *(const bf16x8*)&vt[(cb * 16 + l15) * 136 + ks * 32 + lh * 8];
                o[cb] = __builtin_amdgcn_mfma_f32_16x16x32_bf16(pa, vb, o[cb], 0, 0, 0);
            }
        }
        __syncthreads();
    }

    float linv[4];
    for (int j = 0; j < 4; j++) linv[j] = 1.f / lbuf[wid * 16 + lh * 4 + j];
    long orow = (long)seg * SEGL + qt * 64 + wid * 16;
    for (int cb = 0; cb < 5; cb++)
        for (int j = 0; j < 4; j++)
            out[(orow + lh * 4 + j) * DIM + h * HD + cb * 16 + l15] =
                (short)f2bf(o[cb][j] * linv[j]);
}

// ---------------------------------------------------------------------------
extern "C" void kernel_launch(void* const* d_in, const int* in_sizes, int n_in,
                              void* d_out, int out_size, void* d_ws, size_t ws_size,
                              hipStream_t stream)
{
    const float* hs = (const float*)d_in[0];
    const float* cs = (const float*)d_in[1];
    const float* sn = (const float*)d_in[2];
    const float* qw = (const float*)d_in[3];
    const float* qb = (const float*)d_in[4];
    const float* pw = (const float*)d_in[5];
    const float* pb = (const float*)d_in[6];
    float* out = (float*)d_out;

    short* hsb = (short*)d_ws;                         // [8192][1280] bf16
    short* qwb = hsb + (long)SEQ * DIM;                // [3840][1280]
    short* pwb = qwb + (long)3 * DIM * DIM;            // [1280][1280]
    short* qbf = pwb + (long)DIM * DIM;                // [8][16][1024][96]
    short* kbf = qbf + (long)NSEG * NH * SEGL * HDP;   // [8][16][1024][96]
    short* vbf = kbf + (long)NSEG * NH * SEGL * HDP;   // [8][16][1024][80]
    short* aob = vbf + (long)NSEG * NH * SEGL * HD;    // [8192][1280] bf16

    prep_kernel<<<dim3(2048), dim3(256), 0, stream>>>(hs, qw, pw, hsb, qwb, pwb, qbf, kbf);
    gemm_kernel<0><<<dim3(30, 64), dim3(256), 0, stream>>>(hsb, qwb, qb, qbf, kbf, vbf, nullptr);
    rope_kernel<<<dim3(SEQ * NH * 40 / 256), dim3(256), 0, stream>>>(qbf, kbf, cs, sn);
    attn_kernel<<<dim3(16, 16, 8), dim3(256), 0, stream>>>(qbf, kbf, vbf, aob);
    gemm_kernel<1><<<dim3(10, 64), dim3(256), 0, stream>>>(aob, pwb, pb, nullptr, nullptr, nullptr, out);
}